// Round 10
// baseline (23.466 us; speedup 1.0000x reference)
//
#include <hip/hip_runtime.h>

#define N 4096
#define M 1024
#define D 64
#define MT 8                              // m-values per thread (was 16)
#define MTILES (M / MT)                   // 128 m-tiles
#define SPLITS 16                         // N-chunks (unchanged)
#define ROWS_PER_BLOCK (N / SPLITS)       // 256
#define ROWS_PER_WAVE  (ROWS_PER_BLOCK/4) // 64
#define NB (ROWS_PER_WAVE / 4)            // 16 four-row batches
#define SITES (M * D)                     // 65536
#define K2_BLOCKS 64

// Register-only 3-input min (v_min3_f32), minnum semantics = fminf twice.
__device__ __forceinline__ float min3f(float a, float b, float c) {
    float d;
    asm("v_min3_f32 %0, %1, %2, %3" : "=v"(d) : "v"(a), "v"(b), "v"(c));
    return d;
}

// K1: partial min over an N-chunk for an 8-m tile, z_masked/z_copy fused.
// grid = 128 m-tiles * 16 splits = 2048 blocks (8 blocks/CU -> 8 waves/SIMD,
// the max), 256 threads, lane = d. min_n (z-e)^2 = min_n (z^2-2ez) + e^2.
// VGPR ~40 naturally -> full occupancy without a launch_bounds cap.
__global__ __launch_bounds__(256) void k_minpart(const float* __restrict__ z,
                                                 const float* __restrict__ e,
                                                 const int* __restrict__ idx,
                                                 float* __restrict__ pout,
                                                 float* __restrict__ out,
                                                 int* __restrict__ counter) {
    const int bid = blockIdx.x;
    if (bid == 0 && threadIdx.x == 0) *counter = 0;   // reset for K2, every call

    // fused elementwise outputs: 128 elements per block (2048 blocks total)
    if (threadIdx.x < 128) {
        const int i = bid * 128 + (int)threadIdx.x;
        const float zv = z[i];
        const int row = i >> 6, dd = i & 63;
        out[1 + i] = (dd < idx[row]) ? zv : 0.0f;   // z_masked
        out[1 + N * D + i] = zv;                    // z_copy
    }

    const int mt   = bid & (MTILES - 1);  // m-tile
    const int s    = bid >> 7;            // split
    const int lane = threadIdx.x & 63;
    const int w    = threadIdx.x >> 6;
    const int m0   = mt * MT;

    float n2e[MT];
#pragma unroll
    for (int j = 0; j < MT; ++j) n2e[j] = -2.0f * e[(m0 + j) * D + lane];

    float acc[MT];
#pragma unroll
    for (int j = 0; j < MT; ++j) acc[j] = 3.4e38f;

    const float* zp = z + (s * ROWS_PER_BLOCK + w * ROWS_PER_WAVE) * D + lane;

    // distance-1 software pipeline (kept from R9; harmless)
    float za = zp[0 * D], zb = zp[1 * D], zc = zp[2 * D], zd = zp[3 * D];
#pragma unroll
    for (int r4 = 0; r4 < NB - 1; ++r4) {
        const float na = zp[(4 * r4 + 4) * D];
        const float nb = zp[(4 * r4 + 5) * D];
        const float nc = zp[(4 * r4 + 6) * D];
        const float nd = zp[(4 * r4 + 7) * D];
        const float za2 = za * za, zb2 = zb * zb;
        const float zc2 = zc * zc, zd2 = zd * zd;
#pragma unroll
        for (int j = 0; j < MT; ++j) {
            const float t1 = fmaf(n2e[j], za, za2);
            const float t2 = fmaf(n2e[j], zb, zb2);
            const float t3 = fmaf(n2e[j], zc, zc2);
            const float t4 = fmaf(n2e[j], zd, zd2);
            acc[j] = min3f(acc[j], min3f(t1, t2, t3), t4);
        }
        za = na; zb = nb; zc = nc; zd = nd;
    }
    {   // epilogue batch
        const float za2 = za * za, zb2 = zb * zb;
        const float zc2 = zc * zc, zd2 = zd * zd;
#pragma unroll
        for (int j = 0; j < MT; ++j) {
            const float t1 = fmaf(n2e[j], za, za2);
            const float t2 = fmaf(n2e[j], zb, zb2);
            const float t3 = fmaf(n2e[j], zc, zc2);
            const float t4 = fmaf(n2e[j], zd, zd2);
            acc[j] = min3f(acc[j], min3f(t1, t2, t3), t4);
        }
    }

    __shared__ float lds[4][MT * 64];   // 8 KB
#pragma unroll
    for (int j = 0; j < MT; ++j) lds[w][j * 64 + lane] = acc[j];
    __syncthreads();
    for (int p = threadIdx.x; p < MT * 64; p += 256) {
        const float v = fminf(fminf(lds[0][p], lds[1][p]),
                              fminf(lds[2][p], lds[3][p]));
        pout[s * SITES + m0 * 64 + p] = v;   // same [s][m][d] layout as champion
    }
}

// K2: champion form, bit-identical. min over 16 splits + e^2, sum; 64 blocks,
// 4 sites/thread; deterministic last-block finish: 64 PARALLEL coherent reads
// + fixed-order shuffle tree.
__global__ __launch_bounds__(256) void k_minsum(const float* __restrict__ pout,
                                                const float* __restrict__ e,
                                                float* __restrict__ bsums,
                                                int* __restrict__ counter,
                                                float* __restrict__ out) {
    const int t = blockIdx.x * 256 + (int)threadIdx.x;  // 16384 threads
    float local = 0.0f;
#pragma unroll
    for (int k = 0; k < 4; ++k) {
        const int site = t + k * 16384;
        float v = 3.4e38f;
#pragma unroll
        for (int si = 0; si < SPLITS; ++si)
            v = fminf(v, pout[si * SITES + site]);
        const float ev = e[site];
        local += v + ev * ev;
    }
#pragma unroll
    for (int off = 32; off > 0; off >>= 1)
        local += __shfl_down(local, off, 64);
    __shared__ float wsum[4];
    __shared__ int is_last;
    const int lane = threadIdx.x & 63, w = threadIdx.x >> 6;
    if (lane == 0) wsum[w] = local;
    __syncthreads();
    if (threadIdx.x == 0) {
        atomicExch(&bsums[blockIdx.x], (wsum[0] + wsum[1]) + (wsum[2] + wsum[3]));
        __threadfence();
        is_last = (atomicAdd(counter, 1) == K2_BLOCKS - 1);
    }
    __syncthreads();
    if (is_last && threadIdx.x < 64) {
        __threadfence();
        float v = atomicAdd(&bsums[threadIdx.x], 0.0f);  // 64 parallel reads
#pragma unroll
        for (int off = 32; off > 0; off >>= 1)
            v += __shfl_down(v, off, 64);
        if (threadIdx.x == 0) out[0] = v * (1.0f / SITES);
    }
}

extern "C" void kernel_launch(void* const* d_in, const int* in_sizes, int n_in,
                              void* d_out, int out_size, void* d_ws, size_t ws_size,
                              hipStream_t stream) {
    const float* z   = (const float*)d_in[0];
    const float* e   = (const float*)d_in[1];
    const int*   idx = (const int*)d_in[2];
    float* out = (float*)d_out;

    float* pout    = (float*)d_ws;                       // 4 MB partials
    float* bsums   = (float*)d_ws + SPLITS * SITES;      // 64 floats
    int*   counter = (int*)(bsums + K2_BLOCKS);

    k_minpart<<<MTILES * SPLITS, 256, 0, stream>>>(z, e, idx, pout, out, counter);
    k_minsum<<<K2_BLOCKS, 256, 0, stream>>>(pout, e, bsums, counter, out);
}